// Round 11
// baseline (281.371 us; speedup 1.0000x reference)
//
#include <hip/hip_runtime.h>

#define NN 50000
#define NE 800000
#define EPSV 1e-5f

typedef unsigned int u32;
typedef short s16x8 __attribute__((ext_vector_type(8)));
typedef float f32x4 __attribute__((ext_vector_type(4)));

// ws layout (4B units):
//   A: aggxb/yb   [NN*64]
//   xb            [NN*32]   (live until k_gemm_a)
//   st            [1024]
//   deg/cur/csr   [NN + NN + NE]
//   psum/pssq     [2*400000] (rank aliases; dead before gemm_a)
//   pedge         [NE]
//   Wpk/Wpk0      [16384 + 8192]
//   hb            [NN*64]   (bf16 layer-0 h; root-half of layer-1 h after gemm_b)
//   hsb           [NN*64]   (bf16 layer-1 h pre-BN, gather2 output)
#define WS_NEEDED \
  ((size_t)(NN * 64 + NN * 32 + 1024 + NN + NN + NE + 2 * 400000 + NE + \
            16384 + 8192 + NN * 64 + NN * 64) * 4)

__global__ void k_fallback(float* __restrict__ out) {
  int i = blockIdx.x * 256 + threadIdx.x;
  if (i < NN * 128) out[i] = 2.0f;
}

// Mode detect (int64 vs int32 edge_index) folded in via wave ballot:
// int64 iff odd 32-bit words of the first 32 entries are all zero
// (identical check to the old k_detect). 2 edges/thread, vector loads.
__global__ __launch_bounds__(256) void k_hist(
    const int* __restrict__ ei,
    int* __restrict__ deg, int* __restrict__ rank, u32* __restrict__ pedge) {
  const int lane = threadIdx.x & 63;
  int odd = (lane < 32) ? ei[2 * lane + 1] : 0;
  unsigned long long b = __ballot(odd == 0);
  const int m = (b == ~0ull) ? 1 : 0;
  int p = blockIdx.x * 256 + threadIdx.x;  // pair index
  int e = p * 2;
  if (e >= NE) return;
  int s0, s1, d0, d1;
  if (m) {
    uint4 sv = *(const uint4*)&ei[e << 1];         // words 2e..2e+3
    uint4 dv = *(const uint4*)&ei[(NE + e) << 1];  // words 2(NE+e)..
    s0 = (int)sv.x; s1 = (int)sv.z;
    d0 = (int)dv.x; d1 = (int)dv.z;
  } else {
    uint2 sv = *(const uint2*)&ei[e];
    uint2 dv = *(const uint2*)&ei[NE + e];
    s0 = (int)sv.x; s1 = (int)sv.y;
    d0 = (int)dv.x; d1 = (int)dv.y;
  }
  s0 = min(max(s0, 0), NN - 1); d0 = min(max(d0, 0), NN - 1);
  s1 = min(max(s1, 0), NN - 1); d1 = min(max(d1, 0), NN - 1);
  int r0 = atomicAdd(&deg[d0], 1);
  int r1 = atomicAdd(&deg[d1], 1);
  *(uint2*)&rank[e] = make_uint2((u32)r0, (u32)r1);
  *(uint2*)&pedge[e] =
      make_uint2(((u32)s0 << 16) | (u32)d0, ((u32)s1 << 16) | (u32)d1);
}

// Stage 1: per-256-chunk sums of deg. 196 blocks.
__global__ __launch_bounds__(256) void k_scan1(
    const int* __restrict__ deg, int* __restrict__ bsum) {
  const int b = blockIdx.x, t = threadIdx.x;
  const int lane = t & 63, wave = t >> 6;
  int idx = b * 256 + t;
  int v = (idx < NN) ? deg[idx] : 0;
  for (int off = 32; off > 0; off >>= 1) v += __shfl_down(v, off);
  __shared__ int wt[4];
  if (lane == 0) wt[wave] = v;
  __syncthreads();
  if (t == 0) bsum[b] = wt[0] + wt[1] + wt[2] + wt[3];
}

// Stage 2: block offset = reduce(bsum[0..b)), then block-wide exclusive scan.
__global__ __launch_bounds__(256) void k_scan3(
    const int* __restrict__ deg, const int* __restrict__ bsum, int* __restrict__ cur) {
  const int b = blockIdx.x, t = threadIdx.x;
  const int lane = t & 63, wave = t >> 6;
  __shared__ int wt[4];
  __shared__ int boff;
  int pv = (t < b) ? bsum[t] : 0;  // b <= 195 < 256
  int r = pv;
  for (int off = 32; off > 0; off >>= 1) r += __shfl_down(r, off);
  if (lane == 0) wt[wave] = r;
  __syncthreads();
  if (t == 0) boff = wt[0] + wt[1] + wt[2] + wt[3];
  __syncthreads();
  int idx = b * 256 + t;
  int v = (idx < NN) ? deg[idx] : 0;
  int incl = v;
  for (int off = 1; off < 64; off <<= 1) {
    int u = __shfl_up(incl, off);
    if (lane >= off) incl += u;
  }
  if (lane == 63) wt[wave] = incl;
  __syncthreads();
  int woff = 0;
  for (int w = 0; w < wave; ++w) woff += wt[w];
  if (idx < NN) cur[idx] = boff + woff + incl - v;  // exclusive start offsets
}

// XCD-affine filtered scatter: 512 blocks = 8 pos-range groups x 64 scan
// slices. Block (g = b&7, s = b>>3) scans slice s of all edges (coalesced,
// L3-served on re-read) and writes only positions in csr range
// [g*NE/8, (g+1)*NE/8) -- 400 KB, resident in one XCD's L2 under the
// round-robin blockIdx->XCD mapping, so dirty lines accumulate ~32 stores
// before writeback (HBM write ~3.2 MB instead of ~51 MB line-amplified).
// Correctness is mapping-independent: each edge passes exactly one filter.
__global__ __launch_bounds__(256) void k_place(
    const u32* __restrict__ pedge, const int* __restrict__ cur,
    const int* __restrict__ rank, int* __restrict__ csr) {
  const int g = blockIdx.x & 7;
  const int s = blockIdx.x >> 3;
  const int lo = g * (NE / 8);
  const int hi = lo + (NE / 8);
  const int base = s * (NE / 64);
  for (int j = threadIdx.x; j < NE / 64; j += 256) {
    int e = base + j;
    u32 pe = pedge[e];
    int dst = (int)(pe & 0xffffu);
    int src = (int)(pe >> 16);
    int pos = cur[dst] + rank[e];
    if (pos >= lo && pos < hi) csr[pos] = src;
  }
}

__device__ __forceinline__ u32 pack_bf16(float lo, float hi) {
  union { float f; u32 u; } a, b;
  a.f = lo; b.f = hi;
  u32 ua = a.u + 0x7fffu + ((a.u >> 16) & 1u);
  u32 ub = b.u + 0x7fffu + ((b.u >> 16) & 1u);
  return (ua >> 16) | (ub & 0xffff0000u);
}
#define BFLO(u) __uint_as_float((u) << 16)
#define BFHI(u) __uint_as_float((u) & 0xffff0000u)

__device__ __forceinline__ void acc4u(float* a, uint2 u) {
  a[0] += BFLO(u.x); a[1] += BFHI(u.x);
  a[2] += BFLO(u.y); a[3] += BFHI(u.y);
}
__device__ __forceinline__ void acc8u(float* a, uint4 v) {
  a[0] += BFLO(v.x); a[1] += BFHI(v.x);
  a[2] += BFLO(v.y); a[3] += BFHI(v.y);
  a[4] += BFLO(v.z); a[5] += BFHI(v.z);
  a[6] += BFLO(v.w); a[7] += BFHI(v.w);
}

// Merged prep: xb pack (blocks 0..6249), Wpk1 pack (6250..6313),
// Wpk0 pack (6314..6345).
__global__ __launch_bounds__(256) void k_prep(
    const float* __restrict__ x, u32* __restrict__ xb,
    const float* __restrict__ Wrel1, const float* __restrict__ Wroot1,
    u32* __restrict__ Wpk,
    const float* __restrict__ Wrel0, const float* __restrict__ Wroot0,
    u32* __restrict__ Wpk0) {
  const int b = blockIdx.x;
  if (b < 6250) {  // xb[n*32+c] = pack(x[n*64+2c], x[n*64+2c+1]) over NN*32
    int i = b * 256 + threadIdx.x;
    int n = i >> 5, c = i & 31;
    float2 v = *(const float2*)&x[n * 64 + c * 2];
    xb[i] = pack_bf16(v.x, v.y);
  } else if (b < 6314) {  // [Wrel1 | Wroot1] -> bf16 B frags (16384 u32)
    int t = (b - 6250) * 256 + threadIdx.x;
    int r = t & 3, lane = (t >> 2) & 63, s = (t >> 8) & 3, nt = t >> 10;
    int k = 32 * s + (lane >> 4) * 8 + 2 * r;
    int col = 16 * nt + (lane & 15);
    const float* W = (col < 128) ? &Wrel1[k * 128 + col]
                                 : &Wroot1[k * 128 + (col - 128)];
    Wpk[t] = pack_bf16(W[0], W[128]);
  } else {  // [Wrel0 ; Wroot0] stacked K -> bf16 B frags (8192 u32)
    int t = (b - 6314) * 256 + threadIdx.x;
    int r = t & 3, lane = (t >> 2) & 63, s = (t >> 8) & 3, nt = t >> 10;
    int k = 32 * s + (lane >> 4) * 8 + 2 * r;
    int col = 16 * nt + (lane & 15);
    const float* W = (k < 64) ? &Wrel0[k * 128 + col]
                              : &Wroot0[(k - 64) * 128 + col];
    Wpk0[t] = pack_bf16(W[0], W[128]);
  }
}

// aggxb = packed-bf16 sums over incoming edges of xb[src]. 16 lanes/node,
// uint2/lane, 4x ILP (4 independent row loads in flight).
__global__ __launch_bounds__(256) void k_gather_xb(
    const u32* __restrict__ xb, const int* __restrict__ csr,
    const int* __restrict__ cur, const int* __restrict__ deg,
    u32* __restrict__ aggxb) {
  int tid = blockIdx.x * 256 + threadIdx.x;
  int n = tid >> 4, L = tid & 15;
  int i = cur[n];
  int end = i + deg[n];
  float acc[4][4];
#pragma unroll
  for (int q = 0; q < 4; ++q)
#pragma unroll
    for (int c = 0; c < 4; ++c) acc[q][c] = 0.f;
  for (; i + 3 < end; i += 4) {
    int s0 = csr[i], s1 = csr[i + 1], s2 = csr[i + 2], s3 = csr[i + 3];
    uint2 u0 = *(const uint2*)&xb[s0 * 32 + 2 * L];
    uint2 u1 = *(const uint2*)&xb[s1 * 32 + 2 * L];
    uint2 u2 = *(const uint2*)&xb[s2 * 32 + 2 * L];
    uint2 u3 = *(const uint2*)&xb[s3 * 32 + 2 * L];
    acc4u(acc[0], u0);
    acc4u(acc[1], u1);
    acc4u(acc[2], u2);
    acc4u(acc[3], u3);
  }
  for (; i < end; ++i) {
    int s = csr[i];
    uint2 u = *(const uint2*)&xb[s * 32 + 2 * L];
    acc4u(acc[0], u);
  }
  float A0 = acc[0][0] + acc[1][0] + acc[2][0] + acc[3][0];
  float A1 = acc[0][1] + acc[1][1] + acc[2][1] + acc[3][1];
  float A2 = acc[0][2] + acc[1][2] + acc[2][2] + acc[3][2];
  float A3 = acc[0][3] + acc[1][3] + acc[2][3] + acc[3][3];
  uint2 o;
  o.x = pack_bf16(A0, A1);
  o.y = pack_bf16(A2, A3);
  *(uint2*)&aggxb[n * 32 + 2 * L] = o;
}

// hb = bf16([aggx | x] @ [Wrel0 ; Wroot0]) (M=NN, K=128, N=128) + BN0 partials.
__global__ __launch_bounds__(256) void k_gemm_a(
    const u32* __restrict__ xb, const u32* __restrict__ aggxb,
    const u32* __restrict__ Wpk0,
    u32* __restrict__ hb, float* __restrict__ psum, float* __restrict__ pssq) {
  __shared__ u32 As[8192];  // 128 rows x 128 k bf16, XOR-swizzled
  const int tid = threadIdx.x;
  const int nb = blockIdx.x * 128;
  char* AsB = (char*)As;
#pragma unroll
  for (int it = 0; it < 16; ++it) {
    int f = tid + 256 * it;          // 0..4095 over [128 rows][32 u32-pairs]
    int row = f >> 5, k4 = f & 31;   // k = 4*k4 .. 4*k4+3
    int n = nb + row;
    const u32* src = (k4 < 16) ? &aggxb[n * 32 + 2 * k4] : &xb[n * 32 + 2 * (k4 - 16)];
    uint2 p = (n < NN) ? *(const uint2*)src : make_uint2(0u, 0u);
    int byte = row * 256 + k4 * 8;
    byte ^= (row & 7) << 4;
    *(uint2*)(AsB + byte) = p;
  }
  __syncthreads();
  const int lane = tid & 63;
  const int w = tid >> 6;
  const int lr = lane & 15;  // A row-in-tile / D col-in-tile
  const int lg = lane >> 4;  // k-group / D row-group
  f32x4 zero = {0.f, 0.f, 0.f, 0.f};
  f32x4 acc[8][2];
#pragma unroll
  for (int m = 0; m < 8; ++m) {
    acc[m][0] = zero;
    acc[m][1] = zero;
  }
#pragma unroll
  for (int s = 0; s < 4; ++s) {
    s16x8 bf[2];
#pragma unroll
    for (int nt = 0; nt < 2; ++nt)
      bf[nt] = *(const s16x8*)&Wpk0[(((2 * w + nt) * 4 + s) * 64 + lane) * 4];
#pragma unroll
    for (int m = 0; m < 8; ++m) {
      int row = 16 * m + lr;
      int byte = row * 256 + 64 * s + 16 * lg;
      byte ^= (row & 7) << 4;
      s16x8 af = *(const s16x8*)(AsB + byte);
      acc[m][0] = __builtin_amdgcn_mfma_f32_16x16x32_bf16(af, bf[0], acc[m][0], 0, 0, 0);
      acc[m][1] = __builtin_amdgcn_mfma_f32_16x16x32_bf16(af, bf[1], acc[m][1], 0, 0, 0);
    }
  }
  // Epilogue 1: BN0 partials from fp32 accs (C layout: col=lane&15, row=4lg+i).
  float ps[2] = {0.f, 0.f}, qs[2] = {0.f, 0.f};
#pragma unroll
  for (int m = 0; m < 8; ++m) {
#pragma unroll
    for (int nt = 0; nt < 2; ++nt) {
#pragma unroll
      for (int i = 0; i < 4; ++i) {
        float a = acc[m][nt][i];
        ps[nt] += a;
        qs[nt] += a * a;
      }
    }
  }
  // Epilogue 2: bf16 store, adjacent-column pairing via shfl_xor(1).
#pragma unroll
  for (int m = 0; m < 8; ++m) {
    int rowb = nb + 16 * m + 4 * lg;
#pragma unroll
    for (int nt = 0; nt < 2; ++nt) {
      int colg = 32 * w + 16 * nt + lr;
      float a0 = acc[m][nt][0], a1 = acc[m][nt][1];
      float a2 = acc[m][nt][2], a3 = acc[m][nt][3];
      float o0 = __shfl_xor(a0, 1), o1 = __shfl_xor(a1, 1);
      float o2 = __shfl_xor(a2, 1), o3 = __shfl_xor(a3, 1);
      int c2 = colg >> 1;
      u32 q0, q1;
      int i0;
      if ((lane & 1) == 0) {
        q0 = pack_bf16(a0, o0); q1 = pack_bf16(a1, o1); i0 = 0;
      } else {
        q0 = pack_bf16(o2, a2); q1 = pack_bf16(o3, a3); i0 = 2;
      }
      int n0 = rowb + i0, n1 = rowb + i0 + 1;
      if (n0 < NN) hb[n0 * 64 + c2] = q0;
      if (n1 < NN) hb[n1 * 64 + c2] = q1;
    }
  }
  __syncthreads();  // safe LDS reuse
  float* S = (float*)As;   // [4][128]
  float* Q = S + 512;      // [4][128]
#pragma unroll
  for (int nt = 0; nt < 2; ++nt) {
    int colg = 32 * w + 16 * nt + lr;
    S[lg * 128 + colg] = ps[nt];
    Q[lg * 128 + colg] = qs[nt];
  }
  __syncthreads();
  if (tid < 128) {
    float s = 0.f, q = 0.f;
#pragma unroll
    for (int g = 0; g < 4; ++g) { s += S[g * 128 + tid]; q += Q[g * 128 + tid]; }
    psum[blockIdx.x * 128 + tid] = s;
    pssq[blockIdx.x * 128 + tid] = q;
  }
}

// Parallel partial reduction -> scale/shift. 128 blocks (one per channel) x 64 lanes.
__global__ __launch_bounds__(64) void k_bnfin(
    const float* __restrict__ psum, const float* __restrict__ pssq,
    const float* __restrict__ gamma, const float* __restrict__ beta,
    float* __restrict__ scale, float* __restrict__ shift, int P) {
  const int c = blockIdx.x;
  const int t = threadIdx.x;
  float S = 0.f, Q = 0.f;
  for (int p = t; p < P; p += 64) {
    S += psum[p * 128 + c];
    Q += pssq[p * 128 + c];
  }
  for (int off = 32; off > 0; off >>= 1) {
    S += __shfl_down(S, off);
    Q += __shfl_down(Q, off);
  }
  if (t == 0) {
    float mean = S * (1.0f / NN);
    float var = fmaxf(Q * (1.0f / NN) - mean * mean, 0.f);
    float sc = gamma[c] * rsqrtf(var + EPSV);
    scale[c] = sc;
    shift[c] = beta[c] - mean * sc;
  }
}

// t = relu(bn(unpack(hb))); yb = bf16(t @ Wrel1); hb <- bf16(t @ Wroot1) in-place.
__global__ __launch_bounds__(256) void k_gemm_b(
    u32* __restrict__ hb, const u32* __restrict__ Wpk,
    const float* __restrict__ scale, const float* __restrict__ shift,
    u32* __restrict__ yb) {
  __shared__ u32 As[4096];  // 64 rows x 128 k bf16, XOR-swizzled
  const int tid = threadIdx.x;
  const int nb = blockIdx.x * 64;
  char* AsB = (char*)As;
#pragma unroll
  for (int it = 0; it < 8; ++it) {
    int f = tid + 256 * it;          // 0..2047 over [64 rows][32 uint2]
    int row = f >> 5, k4 = f & 31;   // channels 4*k4 .. 4*k4+3
    int n = nb + row;
    uint2 v = (n < NN) ? *(const uint2*)&hb[n * 64 + 2 * k4] : make_uint2(0u, 0u);
    float4 sc = *(const float4*)&scale[4 * k4];
    float4 sh = *(const float4*)&shift[4 * k4];
    float t0 = fmaxf(BFLO(v.x) * sc.x + sh.x, 0.f);
    float t1 = fmaxf(BFHI(v.x) * sc.y + sh.y, 0.f);
    float t2 = fmaxf(BFLO(v.y) * sc.z + sh.z, 0.f);
    float t3 = fmaxf(BFHI(v.y) * sc.w + sh.w, 0.f);
    uint2 p;
    p.x = pack_bf16(t0, t1);
    p.y = pack_bf16(t2, t3);
    int byte = row * 256 + k4 * 8;
    byte ^= (row & 7) << 4;
    *(uint2*)(AsB + byte) = p;
  }
  __syncthreads();
  const int lane = tid & 63;
  const int w = tid >> 6;
  const int lr = lane & 15;  // A row-in-tile / B,D col-in-tile
  const int lg = lane >> 4;  // k-group
  f32x4 zero = {0.f, 0.f, 0.f, 0.f};
  f32x4 acc[4][4];
#pragma unroll
  for (int m = 0; m < 4; ++m)
#pragma unroll
    for (int nt = 0; nt < 4; ++nt) acc[m][nt] = zero;

#pragma unroll
  for (int s = 0; s < 4; ++s) {
    s16x8 af[4];
#pragma unroll
    for (int m = 0; m < 4; ++m) {
      int row = 16 * m + lr;
      int byte = row * 256 + 64 * s + 16 * lg;
      byte ^= (row & 7) << 4;
      af[m] = *(const s16x8*)(AsB + byte);
    }
    s16x8 bf[4];
#pragma unroll
    for (int nt = 0; nt < 4; ++nt) {
      int gnt = w * 4 + nt;
      bf[nt] = *(const s16x8*)&Wpk[((gnt * 4 + s) * 64 + lane) * 4];
    }
#pragma unroll
    for (int m = 0; m < 4; ++m)
#pragma unroll
      for (int nt = 0; nt < 4; ++nt)
        acc[m][nt] = __builtin_amdgcn_mfma_f32_16x16x32_bf16(
            af[m], bf[nt], acc[m][nt], 0, 0, 0);
  }
  // Unified epilogue: bf16 pairs; w<2 -> yb (cols 0..127), w>=2 -> hb (cols 128..255).
  u32* dstp = (w < 2) ? yb : hb;
  const int cbase = (w < 2) ? 64 * w : 64 * (w - 2);
#pragma unroll
  for (int m = 0; m < 4; ++m) {
#pragma unroll
    for (int nt = 0; nt < 4; ++nt) {
      int colg = cbase + 16 * nt + lr;
      int rowb = nb + 16 * m + 4 * lg;
      float a0 = acc[m][nt][0], a1 = acc[m][nt][1];
      float a2 = acc[m][nt][2], a3 = acc[m][nt][3];
      float o0 = __shfl_xor(a0, 1), o1 = __shfl_xor(a1, 1);
      float o2 = __shfl_xor(a2, 1), o3 = __shfl_xor(a3, 1);
      int c2 = colg >> 1;
      u32 q0, q1;
      int i0;
      if ((lane & 1) == 0) {
        q0 = pack_bf16(a0, o0); q1 = pack_bf16(a1, o1); i0 = 0;
      } else {
        q0 = pack_bf16(o2, a2); q1 = pack_bf16(o3, a3); i0 = 2;
      }
      int n0 = rowb + i0, n1 = rowb + i0 + 1;
      if (n0 < NN) dstp[n0 * 64 + c2] = q0;
      if (n1 < NN) dstp[n1 * 64 + c2] = q1;
    }
  }
}

// hsb[n] = bf16( unpack(hb_root[n]) + sum over edges of unpack(yb[src]) )
// + fused BN1 stat partials (fp32). 16 lanes/node, uint4/lane, 4x ILP.
__global__ __launch_bounds__(256) void k_gather2(
    const u32* __restrict__ yb, const int* __restrict__ csr,
    const int* __restrict__ cur, const int* __restrict__ deg,
    const u32* __restrict__ hroot, u32* __restrict__ hsb,
    float* __restrict__ psum, float* __restrict__ pssq) {
  int tid = blockIdx.x * 256 + threadIdx.x;
  int n = tid >> 4;
  int L = threadIdx.x & 15;
  int base = L << 2;   // u32 index within row
  int c0 = L << 3;     // first channel handled by this lane
  int i = cur[n];
  int end = i + deg[n];
  float acc[4][8];
#pragma unroll
  for (int q = 0; q < 4; ++q)
#pragma unroll
    for (int c = 0; c < 8; ++c) acc[q][c] = 0.f;
  for (; i + 3 < end; i += 4) {
    int s0 = csr[i], s1 = csr[i + 1], s2 = csr[i + 2], s3 = csr[i + 3];
    uint4 v0 = *(const uint4*)&yb[s0 * 64 + base];
    uint4 v1 = *(const uint4*)&yb[s1 * 64 + base];
    uint4 v2 = *(const uint4*)&yb[s2 * 64 + base];
    uint4 v3 = *(const uint4*)&yb[s3 * 64 + base];
    acc8u(acc[0], v0);
    acc8u(acc[1], v1);
    acc8u(acc[2], v2);
    acc8u(acc[3], v3);
  }
  for (; i < end; ++i) {
    int s = csr[i];
    uint4 v = *(const uint4*)&yb[s * 64 + base];
    acc8u(acc[0], v);
  }
  float A[8];
#pragma unroll
  for (int c = 0; c < 8; ++c)
    A[c] = acc[0][c] + acc[1][c] + acc[2][c] + acc[3][c];
  uint4 hv = *(const uint4*)&hroot[n * 64 + base];
  float4 R0 = make_float4(BFLO(hv.x) + A[0], BFHI(hv.x) + A[1],
                          BFLO(hv.y) + A[2], BFHI(hv.y) + A[3]);
  float4 R1 = make_float4(BFLO(hv.z) + A[4], BFHI(hv.z) + A[5],
                          BFLO(hv.w) + A[6], BFHI(hv.w) + A[7]);
  uint4 ov;
  ov.x = pack_bf16(R0.x, R0.y);
  ov.y = pack_bf16(R0.z, R0.w);
  ov.z = pack_bf16(R1.x, R1.y);
  ov.w = pack_bf16(R1.z, R1.w);
  *(uint4*)&hsb[n * 64 + base] = ov;
  // Fused BN1 stat partials (fp32, pre-rounding): 16 nodes x 128 channels.
  __shared__ float S[16 * 132], Q[16 * 132];
  const int nl = threadIdx.x >> 4;
  *(float4*)&S[nl * 132 + c0]     = R0;
  *(float4*)&S[nl * 132 + c0 + 4] = R1;
  *(float4*)&Q[nl * 132 + c0] =
      make_float4(R0.x * R0.x, R0.y * R0.y, R0.z * R0.z, R0.w * R0.w);
  *(float4*)&Q[nl * 132 + c0 + 4] =
      make_float4(R1.x * R1.x, R1.y * R1.y, R1.z * R1.z, R1.w * R1.w);
  __syncthreads();
  const int t = threadIdx.x;
  if (t < 128) {
    float s = 0.f, q = 0.f;
#pragma unroll
    for (int g = 0; g < 16; ++g) { s += S[g * 132 + t]; q += Q[g * 132 + t]; }
    psum[blockIdx.x * 128 + t] = s;
    pssq[blockIdx.x * 128 + t] = q;
  }
}

// out = bn1(unpack(hsb)). NN*16 threads, 8 channels/thread.
__global__ __launch_bounds__(256) void k_final(
    const u32* __restrict__ hsb, const float* __restrict__ scale,
    const float* __restrict__ shift, float* __restrict__ out) {
  int tid = blockIdx.x * 256 + threadIdx.x;  // over NN*16
  int n = tid >> 4, L = tid & 15;
  int c0 = L << 3;
  uint4 v = *(const uint4*)&hsb[n * 64 + (L << 2)];
  float4 s0 = *(const float4*)&scale[c0];
  float4 s1 = *(const float4*)&scale[c0 + 4];
  float4 h0 = *(const float4*)&shift[c0];
  float4 h1 = *(const float4*)&shift[c0 + 4];
  float4 o0 = make_float4(BFLO(v.x) * s0.x + h0.x, BFHI(v.x) * s0.y + h0.y,
                          BFLO(v.y) * s0.z + h0.z, BFHI(v.y) * s0.w + h0.w);
  float4 o1 = make_float4(BFLO(v.z) * s1.x + h1.x, BFHI(v.z) * s1.y + h1.y,
                          BFLO(v.w) * s1.z + h1.z, BFHI(v.w) * s1.w + h1.w);
  *(float4*)&out[n * 128 + c0]     = o0;
  *(float4*)&out[n * 128 + c0 + 4] = o1;
}

extern "C" void kernel_launch(void* const* d_in, const int* in_sizes, int n_in,
                              void* d_out, int out_size, void* d_ws, size_t ws_size,
                              hipStream_t stream) {
  if (ws_size < WS_NEEDED) {
    k_fallback<<<(NN * 128 + 255) / 256, 256, 0, stream>>>((float*)d_out);
    return;
  }
  const float* x      = (const float*)d_in[0];
  const int*   ei     = (const int*)d_in[1];
  const float* Wrel0  = (const float*)d_in[2];
  // d_in[3] = b_rel0: per-channel constant pre-BN -> cancels in BN, unused
  const float* Wroot0 = (const float*)d_in[4];
  const float* gamma0 = (const float*)d_in[5];
  const float* beta0  = (const float*)d_in[6];
  const float* Wrel1  = (const float*)d_in[7];
  // d_in[8] = b_rel1: unused (cancels in BN)
  const float* Wroot1 = (const float*)d_in[9];
  const float* gamma1 = (const float*)d_in[10];
  const float* beta1  = (const float*)d_in[11];

  u32*   aggxb = (u32*)d_ws;             // NN*32 u32 (region holds yb NN*64 later)
  u32*   yb   = (u32*)d_ws;              // NN*64 u32 (after gemm_a)
  u32*   xb   = (u32*)((float*)d_ws + NN * 64);  // NN*32, live through gemm_a
  float* st   = (float*)(xb + NN * 32);  // 1024 floats
  float* scale0 = st;       float* shift0 = st + 128;
  float* scale1 = st + 256; float* shift1 = st + 384;
  int* bsum = (int*)(st + 576);          // 196 ints
  int* deg = (int*)(st + 1024);          // NN
  int* cur = deg + NN;                   // NN
  int* csr = cur + NN;                   // NE
  float* psum = (float*)(csr + NE);      // 400000 (3125*128)
  float* pssq = psum + 400000;           // 400000
  int* rank = (int*)psum;                // NE ints (spans psum+pssq); dead later
  u32* pedge = (u32*)(pssq + 400000);    // NE packed edges (src<<16|dst)
  u32* Wpk  = pedge + NE;                // 16384 u32, layer-1 B frags
  u32* Wpk0 = Wpk + 16384;               // 8192 u32, layer-0 B frags
  u32* hb   = Wpk0 + 8192;               // NN*64 u32, bf16 layer-0 h / root-half h
  u32* hsb  = hb + NN * 64;              // NN*64 u32, bf16 layer-1 h pre-BN
  float* h = (float*)d_out;              // final output only

  hipMemsetAsync(deg, 0, (size_t)NN * 4, stream);
  k_hist<<<(NE / 2 + 255) / 256, 256, 0, stream>>>(ei, deg, rank, pedge);
  k_scan1<<<196, 256, 0, stream>>>(deg, bsum);
  k_scan3<<<196, 256, 0, stream>>>(deg, bsum, cur);
  k_place<<<512, 256, 0, stream>>>(pedge, cur, rank, csr);

  k_prep<<<6346, 256, 0, stream>>>(x, xb, Wrel1, Wroot1, Wpk, Wrel0, Wroot0, Wpk0);
  k_gather_xb<<<(NN * 16) / 256, 256, 0, stream>>>(xb, csr, cur, deg, aggxb);
  k_gemm_a<<<(NN + 127) / 128, 256, 0, stream>>>(xb, aggxb, Wpk0, hb, psum, pssq);
  k_bnfin<<<128, 64, 0, stream>>>(psum, pssq, gamma0, beta0, scale0, shift0, 391);
  k_gemm_b<<<(NN + 63) / 64, 256, 0, stream>>>(hb, Wpk, scale0, shift0, yb);
  k_gather2<<<(NN * 16) / 256, 256, 0, stream>>>(yb, csr, cur, deg, hb, hsb, psum, pssq);
  k_bnfin<<<128, 64, 0, stream>>>(psum, pssq, gamma1, beta1, scale1, shift1, 3125);
  k_final<<<(NN * 16) / 256, 256, 0, stream>>>(hsb, scale1, shift1, h);
}

// Round 12
// 259.751 us; speedup vs baseline: 1.0832x; 1.0832x over previous
//
#include <hip/hip_runtime.h>

#define NN 50000
#define NE 800000
#define EPSV 1e-5f

typedef unsigned int u32;
typedef short s16x8 __attribute__((ext_vector_type(8)));
typedef float f32x4 __attribute__((ext_vector_type(4)));

// ws layout (4B units):
//   A: aggxb/yb   [NN*64]
//   xb            [NN*32]   (live until k_gemm_a)
//   st            [1024]
//   deg/cur/csr   [NN + NN + NE]
//   psum/pssq     [2*400000] (rank aliases; dead before gemm_a)
//   pedge         [NE]
//   Wpk/Wpk0      [16384 + 8192]
//   hb            [NN*64]   (bf16 layer-0 h; root-half of layer-1 h after gemm_b)
//   hsb           [NN*64]   (bf16 layer-1 h pre-BN, gather2 output)
#define WS_NEEDED \
  ((size_t)(NN * 64 + NN * 32 + 1024 + NN + NN + NE + 2 * 400000 + NE + \
            16384 + 8192 + NN * 64 + NN * 64) * 4)

__global__ void k_fallback(float* __restrict__ out) {
  int i = blockIdx.x * 256 + threadIdx.x;
  if (i < NN * 128) out[i] = 2.0f;
}

// Mode detect (int64 vs int32 edge_index) folded in via wave ballot:
// int64 iff odd 32-bit words of the first 32 entries are all zero
// (identical check to the old k_detect). 2 edges/thread, vector loads.
__global__ __launch_bounds__(256) void k_hist(
    const int* __restrict__ ei,
    int* __restrict__ deg, int* __restrict__ rank, u32* __restrict__ pedge) {
  const int lane = threadIdx.x & 63;
  int odd = (lane < 32) ? ei[2 * lane + 1] : 0;
  unsigned long long b = __ballot(odd == 0);
  const int m = (b == ~0ull) ? 1 : 0;
  int p = blockIdx.x * 256 + threadIdx.x;  // pair index
  int e = p * 2;
  if (e >= NE) return;
  int s0, s1, d0, d1;
  if (m) {
    uint4 sv = *(const uint4*)&ei[e << 1];         // words 2e..2e+3
    uint4 dv = *(const uint4*)&ei[(NE + e) << 1];  // words 2(NE+e)..
    s0 = (int)sv.x; s1 = (int)sv.z;
    d0 = (int)dv.x; d1 = (int)dv.z;
  } else {
    uint2 sv = *(const uint2*)&ei[e];
    uint2 dv = *(const uint2*)&ei[NE + e];
    s0 = (int)sv.x; s1 = (int)sv.y;
    d0 = (int)dv.x; d1 = (int)dv.y;
  }
  s0 = min(max(s0, 0), NN - 1); d0 = min(max(d0, 0), NN - 1);
  s1 = min(max(s1, 0), NN - 1); d1 = min(max(d1, 0), NN - 1);
  int r0 = atomicAdd(&deg[d0], 1);
  int r1 = atomicAdd(&deg[d1], 1);
  *(uint2*)&rank[e] = make_uint2((u32)r0, (u32)r1);
  *(uint2*)&pedge[e] =
      make_uint2(((u32)s0 << 16) | (u32)d0, ((u32)s1 << 16) | (u32)d1);
}

// Stage 1: per-256-chunk sums of deg. 196 blocks.
__global__ __launch_bounds__(256) void k_scan1(
    const int* __restrict__ deg, int* __restrict__ bsum) {
  const int b = blockIdx.x, t = threadIdx.x;
  const int lane = t & 63, wave = t >> 6;
  int idx = b * 256 + t;
  int v = (idx < NN) ? deg[idx] : 0;
  for (int off = 32; off > 0; off >>= 1) v += __shfl_down(v, off);
  __shared__ int wt[4];
  if (lane == 0) wt[wave] = v;
  __syncthreads();
  if (t == 0) bsum[b] = wt[0] + wt[1] + wt[2] + wt[3];
}

// Stage 2: block offset = reduce(bsum[0..b)), then block-wide exclusive scan.
__global__ __launch_bounds__(256) void k_scan3(
    const int* __restrict__ deg, const int* __restrict__ bsum, int* __restrict__ cur) {
  const int b = blockIdx.x, t = threadIdx.x;
  const int lane = t & 63, wave = t >> 6;
  __shared__ int wt[4];
  __shared__ int boff;
  int pv = (t < b) ? bsum[t] : 0;  // b <= 195 < 256
  int r = pv;
  for (int off = 32; off > 0; off >>= 1) r += __shfl_down(r, off);
  if (lane == 0) wt[wave] = r;
  __syncthreads();
  if (t == 0) boff = wt[0] + wt[1] + wt[2] + wt[3];
  __syncthreads();
  int idx = b * 256 + t;
  int v = (idx < NN) ? deg[idx] : 0;
  int incl = v;
  for (int off = 1; off < 64; off <<= 1) {
    int u = __shfl_up(incl, off);
    if (lane >= off) incl += u;
  }
  if (lane == 63) wt[wave] = incl;
  __syncthreads();
  int woff = 0;
  for (int w = 0; w < wave; ++w) woff += wt[w];
  if (idx < NN) cur[idx] = boff + woff + incl - v;  // exclusive start offsets
}

// Atomic-free: pos = start[dst] + rank[e]. 2 edges/thread, vector loads.
// (Round-10 proven version; binning (r5) and XCD-filter (r11) both regressed.)
__global__ __launch_bounds__(256) void k_place(
    const u32* __restrict__ pedge, const int* __restrict__ cur,
    const int* __restrict__ rank, int* __restrict__ csr) {
  int p = blockIdx.x * 256 + threadIdx.x;
  int e = p * 2;
  if (e >= NE) return;
  uint2 pe = *(const uint2*)&pedge[e];
  uint2 rk = *(const uint2*)&rank[e];
  int d0 = (int)(pe.x & 0xffffu), s0 = (int)(pe.x >> 16);
  int d1 = (int)(pe.y & 0xffffu), s1 = (int)(pe.y >> 16);
  csr[cur[d0] + (int)rk.x] = s0;
  csr[cur[d1] + (int)rk.y] = s1;
}

__device__ __forceinline__ u32 pack_bf16(float lo, float hi) {
  union { float f; u32 u; } a, b;
  a.f = lo; b.f = hi;
  u32 ua = a.u + 0x7fffu + ((a.u >> 16) & 1u);
  u32 ub = b.u + 0x7fffu + ((b.u >> 16) & 1u);
  return (ua >> 16) | (ub & 0xffff0000u);
}
#define BFLO(u) __uint_as_float((u) << 16)
#define BFHI(u) __uint_as_float((u) & 0xffff0000u)

__device__ __forceinline__ void acc4u(float* a, uint2 u) {
  a[0] += BFLO(u.x); a[1] += BFHI(u.x);
  a[2] += BFLO(u.y); a[3] += BFHI(u.y);
}
__device__ __forceinline__ void acc8u(float* a, uint4 v) {
  a[0] += BFLO(v.x); a[1] += BFHI(v.x);
  a[2] += BFLO(v.y); a[3] += BFHI(v.y);
  a[4] += BFLO(v.z); a[5] += BFHI(v.z);
  a[6] += BFLO(v.w); a[7] += BFHI(v.w);
}

// Merged prep: xb pack (blocks 0..6249), Wpk1 pack (6250..6313),
// Wpk0 pack (6314..6345).
__global__ __launch_bounds__(256) void k_prep(
    const float* __restrict__ x, u32* __restrict__ xb,
    const float* __restrict__ Wrel1, const float* __restrict__ Wroot1,
    u32* __restrict__ Wpk,
    const float* __restrict__ Wrel0, const float* __restrict__ Wroot0,
    u32* __restrict__ Wpk0) {
  const int b = blockIdx.x;
  if (b < 6250) {  // xb[n*32+c] = pack(x[n*64+2c], x[n*64+2c+1]) over NN*32
    int i = b * 256 + threadIdx.x;
    int n = i >> 5, c = i & 31;
    float2 v = *(const float2*)&x[n * 64 + c * 2];
    xb[i] = pack_bf16(v.x, v.y);
  } else if (b < 6314) {  // [Wrel1 | Wroot1] -> bf16 B frags (16384 u32)
    int t = (b - 6250) * 256 + threadIdx.x;
    int r = t & 3, lane = (t >> 2) & 63, s = (t >> 8) & 3, nt = t >> 10;
    int k = 32 * s + (lane >> 4) * 8 + 2 * r;
    int col = 16 * nt + (lane & 15);
    const float* W = (col < 128) ? &Wrel1[k * 128 + col]
                                 : &Wroot1[k * 128 + (col - 128)];
    Wpk[t] = pack_bf16(W[0], W[128]);
  } else {  // [Wrel0 ; Wroot0] stacked K -> bf16 B frags (8192 u32)
    int t = (b - 6314) * 256 + threadIdx.x;
    int r = t & 3, lane = (t >> 2) & 63, s = (t >> 8) & 3, nt = t >> 10;
    int k = 32 * s + (lane >> 4) * 8 + 2 * r;
    int col = 16 * nt + (lane & 15);
    const float* W = (k < 64) ? &Wrel0[k * 128 + col]
                              : &Wroot0[(k - 64) * 128 + col];
    Wpk0[t] = pack_bf16(W[0], W[128]);
  }
}

// aggxb = packed-bf16 sums over incoming edges of xb[src]. 16 lanes/node,
// uint2/lane, 4x ILP (4 independent row loads in flight).
__global__ __launch_bounds__(256) void k_gather_xb(
    const u32* __restrict__ xb, const int* __restrict__ csr,
    const int* __restrict__ cur, const int* __restrict__ deg,
    u32* __restrict__ aggxb) {
  int tid = blockIdx.x * 256 + threadIdx.x;
  int n = tid >> 4, L = tid & 15;
  int i = cur[n];
  int end = i + deg[n];
  float acc[4][4];
#pragma unroll
  for (int q = 0; q < 4; ++q)
#pragma unroll
    for (int c = 0; c < 4; ++c) acc[q][c] = 0.f;
  for (; i + 3 < end; i += 4) {
    int s0 = csr[i], s1 = csr[i + 1], s2 = csr[i + 2], s3 = csr[i + 3];
    uint2 u0 = *(const uint2*)&xb[s0 * 32 + 2 * L];
    uint2 u1 = *(const uint2*)&xb[s1 * 32 + 2 * L];
    uint2 u2 = *(const uint2*)&xb[s2 * 32 + 2 * L];
    uint2 u3 = *(const uint2*)&xb[s3 * 32 + 2 * L];
    acc4u(acc[0], u0);
    acc4u(acc[1], u1);
    acc4u(acc[2], u2);
    acc4u(acc[3], u3);
  }
  for (; i < end; ++i) {
    int s = csr[i];
    uint2 u = *(const uint2*)&xb[s * 32 + 2 * L];
    acc4u(acc[0], u);
  }
  float A0 = acc[0][0] + acc[1][0] + acc[2][0] + acc[3][0];
  float A1 = acc[0][1] + acc[1][1] + acc[2][1] + acc[3][1];
  float A2 = acc[0][2] + acc[1][2] + acc[2][2] + acc[3][2];
  float A3 = acc[0][3] + acc[1][3] + acc[2][3] + acc[3][3];
  uint2 o;
  o.x = pack_bf16(A0, A1);
  o.y = pack_bf16(A2, A3);
  *(uint2*)&aggxb[n * 32 + 2 * L] = o;
}

// hb = bf16([aggx | x] @ [Wrel0 ; Wroot0]) (M=NN, K=128, N=128) + BN0 partials.
__global__ __launch_bounds__(256) void k_gemm_a(
    const u32* __restrict__ xb, const u32* __restrict__ aggxb,
    const u32* __restrict__ Wpk0,
    u32* __restrict__ hb, float* __restrict__ psum, float* __restrict__ pssq) {
  __shared__ u32 As[8192];  // 128 rows x 128 k bf16, XOR-swizzled
  const int tid = threadIdx.x;
  const int nb = blockIdx.x * 128;
  char* AsB = (char*)As;
#pragma unroll
  for (int it = 0; it < 16; ++it) {
    int f = tid + 256 * it;          // 0..4095 over [128 rows][32 u32-pairs]
    int row = f >> 5, k4 = f & 31;   // k = 4*k4 .. 4*k4+3
    int n = nb + row;
    const u32* src = (k4 < 16) ? &aggxb[n * 32 + 2 * k4] : &xb[n * 32 + 2 * (k4 - 16)];
    uint2 p = (n < NN) ? *(const uint2*)src : make_uint2(0u, 0u);
    int byte = row * 256 + k4 * 8;
    byte ^= (row & 7) << 4;
    *(uint2*)(AsB + byte) = p;
  }
  __syncthreads();
  const int lane = tid & 63;
  const int w = tid >> 6;
  const int lr = lane & 15;  // A row-in-tile / D col-in-tile
  const int lg = lane >> 4;  // k-group / D row-group
  f32x4 zero = {0.f, 0.f, 0.f, 0.f};
  f32x4 acc[8][2];
#pragma unroll
  for (int m = 0; m < 8; ++m) {
    acc[m][0] = zero;
    acc[m][1] = zero;
  }
#pragma unroll
  for (int s = 0; s < 4; ++s) {
    s16x8 bf[2];
#pragma unroll
    for (int nt = 0; nt < 2; ++nt)
      bf[nt] = *(const s16x8*)&Wpk0[(((2 * w + nt) * 4 + s) * 64 + lane) * 4];
#pragma unroll
    for (int m = 0; m < 8; ++m) {
      int row = 16 * m + lr;
      int byte = row * 256 + 64 * s + 16 * lg;
      byte ^= (row & 7) << 4;
      s16x8 af = *(const s16x8*)(AsB + byte);
      acc[m][0] = __builtin_amdgcn_mfma_f32_16x16x32_bf16(af, bf[0], acc[m][0], 0, 0, 0);
      acc[m][1] = __builtin_amdgcn_mfma_f32_16x16x32_bf16(af, bf[1], acc[m][1], 0, 0, 0);
    }
  }
  // Epilogue 1: BN0 partials from fp32 accs (C layout: col=lane&15, row=4lg+i).
  float ps[2] = {0.f, 0.f}, qs[2] = {0.f, 0.f};
#pragma unroll
  for (int m = 0; m < 8; ++m) {
#pragma unroll
    for (int nt = 0; nt < 2; ++nt) {
#pragma unroll
      for (int i = 0; i < 4; ++i) {
        float a = acc[m][nt][i];
        ps[nt] += a;
        qs[nt] += a * a;
      }
    }
  }
  // Epilogue 2: bf16 store, adjacent-column pairing via shfl_xor(1).
#pragma unroll
  for (int m = 0; m < 8; ++m) {
    int rowb = nb + 16 * m + 4 * lg;
#pragma unroll
    for (int nt = 0; nt < 2; ++nt) {
      int colg = 32 * w + 16 * nt + lr;
      float a0 = acc[m][nt][0], a1 = acc[m][nt][1];
      float a2 = acc[m][nt][2], a3 = acc[m][nt][3];
      float o0 = __shfl_xor(a0, 1), o1 = __shfl_xor(a1, 1);
      float o2 = __shfl_xor(a2, 1), o3 = __shfl_xor(a3, 1);
      int c2 = colg >> 1;
      u32 q0, q1;
      int i0;
      if ((lane & 1) == 0) {
        q0 = pack_bf16(a0, o0); q1 = pack_bf16(a1, o1); i0 = 0;
      } else {
        q0 = pack_bf16(o2, a2); q1 = pack_bf16(o3, a3); i0 = 2;
      }
      int n0 = rowb + i0, n1 = rowb + i0 + 1;
      if (n0 < NN) hb[n0 * 64 + c2] = q0;
      if (n1 < NN) hb[n1 * 64 + c2] = q1;
    }
  }
  __syncthreads();  // safe LDS reuse
  float* S = (float*)As;   // [4][128]
  float* Q = S + 512;      // [4][128]
#pragma unroll
  for (int nt = 0; nt < 2; ++nt) {
    int colg = 32 * w + 16 * nt + lr;
    S[lg * 128 + colg] = ps[nt];
    Q[lg * 128 + colg] = qs[nt];
  }
  __syncthreads();
  if (tid < 128) {
    float s = 0.f, q = 0.f;
#pragma unroll
    for (int g = 0; g < 4; ++g) { s += S[g * 128 + tid]; q += Q[g * 128 + tid]; }
    psum[blockIdx.x * 128 + tid] = s;
    pssq[blockIdx.x * 128 + tid] = q;
  }
}

// Parallel partial reduction -> scale/shift. 128 blocks (one per channel) x 64 lanes.
__global__ __launch_bounds__(64) void k_bnfin(
    const float* __restrict__ psum, const float* __restrict__ pssq,
    const float* __restrict__ gamma, const float* __restrict__ beta,
    float* __restrict__ scale, float* __restrict__ shift, int P) {
  const int c = blockIdx.x;
  const int t = threadIdx.x;
  float S = 0.f, Q = 0.f;
  for (int p = t; p < P; p += 64) {
    S += psum[p * 128 + c];
    Q += pssq[p * 128 + c];
  }
  for (int off = 32; off > 0; off >>= 1) {
    S += __shfl_down(S, off);
    Q += __shfl_down(Q, off);
  }
  if (t == 0) {
    float mean = S * (1.0f / NN);
    float var = fmaxf(Q * (1.0f / NN) - mean * mean, 0.f);
    float sc = gamma[c] * rsqrtf(var + EPSV);
    scale[c] = sc;
    shift[c] = beta[c] - mean * sc;
  }
}

// t = relu(bn(unpack(hb))); yb = bf16(t @ Wrel1); hb <- bf16(t @ Wroot1) in-place.
__global__ __launch_bounds__(256) void k_gemm_b(
    u32* __restrict__ hb, const u32* __restrict__ Wpk,
    const float* __restrict__ scale, const float* __restrict__ shift,
    u32* __restrict__ yb) {
  __shared__ u32 As[4096];  // 64 rows x 128 k bf16, XOR-swizzled
  const int tid = threadIdx.x;
  const int nb = blockIdx.x * 64;
  char* AsB = (char*)As;
#pragma unroll
  for (int it = 0; it < 8; ++it) {
    int f = tid + 256 * it;          // 0..2047 over [64 rows][32 uint2]
    int row = f >> 5, k4 = f & 31;   // channels 4*k4 .. 4*k4+3
    int n = nb + row;
    uint2 v = (n < NN) ? *(const uint2*)&hb[n * 64 + 2 * k4] : make_uint2(0u, 0u);
    float4 sc = *(const float4*)&scale[4 * k4];
    float4 sh = *(const float4*)&shift[4 * k4];
    float t0 = fmaxf(BFLO(v.x) * sc.x + sh.x, 0.f);
    float t1 = fmaxf(BFHI(v.x) * sc.y + sh.y, 0.f);
    float t2 = fmaxf(BFLO(v.y) * sc.z + sh.z, 0.f);
    float t3 = fmaxf(BFHI(v.y) * sc.w + sh.w, 0.f);
    uint2 p;
    p.x = pack_bf16(t0, t1);
    p.y = pack_bf16(t2, t3);
    int byte = row * 256 + k4 * 8;
    byte ^= (row & 7) << 4;
    *(uint2*)(AsB + byte) = p;
  }
  __syncthreads();
  const int lane = tid & 63;
  const int w = tid >> 6;
  const int lr = lane & 15;  // A row-in-tile / B,D col-in-tile
  const int lg = lane >> 4;  // k-group
  f32x4 zero = {0.f, 0.f, 0.f, 0.f};
  f32x4 acc[4][4];
#pragma unroll
  for (int m = 0; m < 4; ++m)
#pragma unroll
    for (int nt = 0; nt < 4; ++nt) acc[m][nt] = zero;

#pragma unroll
  for (int s = 0; s < 4; ++s) {
    s16x8 af[4];
#pragma unroll
    for (int m = 0; m < 4; ++m) {
      int row = 16 * m + lr;
      int byte = row * 256 + 64 * s + 16 * lg;
      byte ^= (row & 7) << 4;
      af[m] = *(const s16x8*)(AsB + byte);
    }
    s16x8 bf[4];
#pragma unroll
    for (int nt = 0; nt < 4; ++nt) {
      int gnt = w * 4 + nt;
      bf[nt] = *(const s16x8*)&Wpk[((gnt * 4 + s) * 64 + lane) * 4];
    }
#pragma unroll
    for (int m = 0; m < 4; ++m)
#pragma unroll
      for (int nt = 0; nt < 4; ++nt)
        acc[m][nt] = __builtin_amdgcn_mfma_f32_16x16x32_bf16(
            af[m], bf[nt], acc[m][nt], 0, 0, 0);
  }
  // Unified epilogue: bf16 pairs; w<2 -> yb (cols 0..127), w>=2 -> hb (cols 128..255).
  u32* dstp = (w < 2) ? yb : hb;
  const int cbase = (w < 2) ? 64 * w : 64 * (w - 2);
#pragma unroll
  for (int m = 0; m < 4; ++m) {
#pragma unroll
    for (int nt = 0; nt < 4; ++nt) {
      int colg = cbase + 16 * nt + lr;
      int rowb = nb + 16 * m + 4 * lg;
      float a0 = acc[m][nt][0], a1 = acc[m][nt][1];
      float a2 = acc[m][nt][2], a3 = acc[m][nt][3];
      float o0 = __shfl_xor(a0, 1), o1 = __shfl_xor(a1, 1);
      float o2 = __shfl_xor(a2, 1), o3 = __shfl_xor(a3, 1);
      int c2 = colg >> 1;
      u32 q0, q1;
      int i0;
      if ((lane & 1) == 0) {
        q0 = pack_bf16(a0, o0); q1 = pack_bf16(a1, o1); i0 = 0;
      } else {
        q0 = pack_bf16(o2, a2); q1 = pack_bf16(o3, a3); i0 = 2;
      }
      int n0 = rowb + i0, n1 = rowb + i0 + 1;
      if (n0 < NN) dstp[n0 * 64 + c2] = q0;
      if (n1 < NN) dstp[n1 * 64 + c2] = q1;
    }
  }
}

// hsb[n] = bf16( unpack(hb_root[n]) + sum over edges of unpack(yb[src]) )
// + fused BN1 stat partials (fp32). 16 lanes/node, uint4/lane, 4x ILP.
__global__ __launch_bounds__(256) void k_gather2(
    const u32* __restrict__ yb, const int* __restrict__ csr,
    const int* __restrict__ cur, const int* __restrict__ deg,
    const u32* __restrict__ hroot, u32* __restrict__ hsb,
    float* __restrict__ psum, float* __restrict__ pssq) {
  int tid = blockIdx.x * 256 + threadIdx.x;
  int n = tid >> 4;
  int L = threadIdx.x & 15;
  int base = L << 2;   // u32 index within row
  int c0 = L << 3;     // first channel handled by this lane
  int i = cur[n];
  int end = i + deg[n];
  float acc[4][8];
#pragma unroll
  for (int q = 0; q < 4; ++q)
#pragma unroll
    for (int c = 0; c < 8; ++c) acc[q][c] = 0.f;
  for (; i + 3 < end; i += 4) {
    int s0 = csr[i], s1 = csr[i + 1], s2 = csr[i + 2], s3 = csr[i + 3];
    uint4 v0 = *(const uint4*)&yb[s0 * 64 + base];
    uint4 v1 = *(const uint4*)&yb[s1 * 64 + base];
    uint4 v2 = *(const uint4*)&yb[s2 * 64 + base];
    uint4 v3 = *(const uint4*)&yb[s3 * 64 + base];
    acc8u(acc[0], v0);
    acc8u(acc[1], v1);
    acc8u(acc[2], v2);
    acc8u(acc[3], v3);
  }
  for (; i < end; ++i) {
    int s = csr[i];
    uint4 v = *(const uint4*)&yb[s * 64 + base];
    acc8u(acc[0], v);
  }
  float A[8];
#pragma unroll
  for (int c = 0; c < 8; ++c)
    A[c] = acc[0][c] + acc[1][c] + acc[2][c] + acc[3][c];
  uint4 hv = *(const uint4*)&hroot[n * 64 + base];
  float4 R0 = make_float4(BFLO(hv.x) + A[0], BFHI(hv.x) + A[1],
                          BFLO(hv.y) + A[2], BFHI(hv.y) + A[3]);
  float4 R1 = make_float4(BFLO(hv.z) + A[4], BFHI(hv.z) + A[5],
                          BFLO(hv.w) + A[6], BFHI(hv.w) + A[7]);
  uint4 ov;
  ov.x = pack_bf16(R0.x, R0.y);
  ov.y = pack_bf16(R0.z, R0.w);
  ov.z = pack_bf16(R1.x, R1.y);
  ov.w = pack_bf16(R1.z, R1.w);
  *(uint4*)&hsb[n * 64 + base] = ov;
  // Fused BN1 stat partials (fp32, pre-rounding): 16 nodes x 128 channels.
  __shared__ float S[16 * 132], Q[16 * 132];
  const int nl = threadIdx.x >> 4;
  *(float4*)&S[nl * 132 + c0]     = R0;
  *(float4*)&S[nl * 132 + c0 + 4] = R1;
  *(float4*)&Q[nl * 132 + c0] =
      make_float4(R0.x * R0.x, R0.y * R0.y, R0.z * R0.z, R0.w * R0.w);
  *(float4*)&Q[nl * 132 + c0 + 4] =
      make_float4(R1.x * R1.x, R1.y * R1.y, R1.z * R1.z, R1.w * R1.w);
  __syncthreads();
  const int t = threadIdx.x;
  if (t < 128) {
    float s = 0.f, q = 0.f;
#pragma unroll
    for (int g = 0; g < 16; ++g) { s += S[g * 132 + t]; q += Q[g * 132 + t]; }
    psum[blockIdx.x * 128 + t] = s;
    pssq[blockIdx.x * 128 + t] = q;
  }
}

// out = bn1(unpack(hsb)). NN*16 threads, 8 channels/thread.
__global__ __launch_bounds__(256) void k_final(
    const u32* __restrict__ hsb, const float* __restrict__ scale,
    const float* __restrict__ shift, float* __restrict__ out) {
  int tid = blockIdx.x * 256 + threadIdx.x;  // over NN*16
  int n = tid >> 4, L = tid & 15;
  int c0 = L << 3;
  uint4 v = *(const uint4*)&hsb[n * 64 + (L << 2)];
  float4 s0 = *(const float4*)&scale[c0];
  float4 s1 = *(const float4*)&scale[c0 + 4];
  float4 h0 = *(const float4*)&shift[c0];
  float4 h1 = *(const float4*)&shift[c0 + 4];
  float4 o0 = make_float4(BFLO(v.x) * s0.x + h0.x, BFHI(v.x) * s0.y + h0.y,
                          BFLO(v.y) * s0.z + h0.z, BFHI(v.y) * s0.w + h0.w);
  float4 o1 = make_float4(BFLO(v.z) * s1.x + h1.x, BFHI(v.z) * s1.y + h1.y,
                          BFLO(v.w) * s1.z + h1.z, BFHI(v.w) * s1.w + h1.w);
  *(float4*)&out[n * 128 + c0]     = o0;
  *(float4*)&out[n * 128 + c0 + 4] = o1;
}

extern "C" void kernel_launch(void* const* d_in, const int* in_sizes, int n_in,
                              void* d_out, int out_size, void* d_ws, size_t ws_size,
                              hipStream_t stream) {
  if (ws_size < WS_NEEDED) {
    k_fallback<<<(NN * 128 + 255) / 256, 256, 0, stream>>>((float*)d_out);
    return;
  }
  const float* x      = (const float*)d_in[0];
  const int*   ei     = (const int*)d_in[1];
  const float* Wrel0  = (const float*)d_in[2];
  // d_in[3] = b_rel0: per-channel constant pre-BN -> cancels in BN, unused
  const float* Wroot0 = (const float*)d_in[4];
  const float* gamma0 = (const float*)d_in[5];
  const float* beta0  = (const float*)d_in[6];
  const float* Wrel1  = (const float*)d_in[7];
  // d_in[8] = b_rel1: unused (cancels in BN)
  const float* Wroot1 = (const float*)d_in[9];
  const float* gamma1 = (const float*)d_in[10];
  const float* beta1  = (const float*)d_in[11];

  u32*   aggxb = (u32*)d_ws;             // NN*32 u32 (region holds yb NN*64 later)
  u32*   yb   = (u32*)d_ws;              // NN*64 u32 (after gemm_a)
  u32*   xb   = (u32*)((float*)d_ws + NN * 64);  // NN*32, live through gemm_a
  float* st   = (float*)(xb + NN * 32);  // 1024 floats
  float* scale0 = st;       float* shift0 = st + 128;
  float* scale1 = st + 256; float* shift1 = st + 384;
  int* bsum = (int*)(st + 576);          // 196 ints
  int* deg = (int*)(st + 1024);          // NN
  int* cur = deg + NN;                   // NN
  int* csr = cur + NN;                   // NE
  float* psum = (float*)(csr + NE);      // 400000 (3125*128)
  float* pssq = psum + 400000;           // 400000
  int* rank = (int*)psum;                // NE ints (spans psum+pssq); dead later
  u32* pedge = (u32*)(pssq + 400000);    // NE packed edges (src<<16|dst)
  u32* Wpk  = pedge + NE;                // 16384 u32, layer-1 B frags
  u32* Wpk0 = Wpk + 16384;               // 8192 u32, layer-0 B frags
  u32* hb   = Wpk0 + 8192;               // NN*64 u32, bf16 layer-0 h / root-half h
  u32* hsb  = hb + NN * 64;              // NN*64 u32, bf16 layer-1 h pre-BN
  float* h = (float*)d_out;              // final output only

  hipMemsetAsync(deg, 0, (size_t)NN * 4, stream);
  k_hist<<<(NE / 2 + 255) / 256, 256, 0, stream>>>(ei, deg, rank, pedge);
  k_scan1<<<196, 256, 0, stream>>>(deg, bsum);
  k_scan3<<<196, 256, 0, stream>>>(deg, bsum, cur);
  k_place<<<(NE / 2 + 255) / 256, 256, 0, stream>>>(pedge, cur, rank, csr);

  k_prep<<<6346, 256, 0, stream>>>(x, xb, Wrel1, Wroot1, Wpk, Wrel0, Wroot0, Wpk0);
  k_gather_xb<<<(NN * 16) / 256, 256, 0, stream>>>(xb, csr, cur, deg, aggxb);
  k_gemm_a<<<(NN + 127) / 128, 256, 0, stream>>>(xb, aggxb, Wpk0, hb, psum, pssq);
  k_bnfin<<<128, 64, 0, stream>>>(psum, pssq, gamma0, beta0, scale0, shift0, 391);
  k_gemm_b<<<(NN + 63) / 64, 256, 0, stream>>>(hb, Wpk, scale0, shift0, yb);
  k_gather2<<<(NN * 16) / 256, 256, 0, stream>>>(yb, csr, cur, deg, hb, hsb, psum, pssq);
  k_bnfin<<<128, 64, 0, stream>>>(psum, pssq, gamma1, beta1, scale1, shift1, 3125);
  k_final<<<(NN * 16) / 256, 256, 0, stream>>>(hsb, scale1, shift1, h);
}